// Round 1
// baseline (1380.960 us; speedup 1.0000x reference)
//
#include <hip/hip_runtime.h>
#include <hip/hip_bf16.h>

// Net_40089224741482: RBF-DQN style forward.
//  values = MLP(s): S->H->H->H->N (relu x3, linear out)
//  h = relu(s@Wl1+bl1); centroids = tanh(h@Wexp[n]+bexp[n])  [B,N,A] (fused, never materialized)
//  dist = sqrt(||c-a||^2 + 0.01); out = softmax(-dist) . values
// Round 1: full fp32 vector pipeline + runtime input-dtype detection (fp32 vs bf16-packed).

namespace {
constexpr int kB = 4096;
constexpr int kS = 128;
constexpr int kA = 32;
constexpr int kH = 1024;
constexpr int kN = 256;

// workspace layout (float offsets)
constexpr size_t OFF_FLAG   = 0;
constexpr size_t OFF_S      = 64;
constexpr size_t OFF_A      = OFF_S    + (size_t)kB * kS;
constexpr size_t OFF_WV1    = OFF_A    + (size_t)kB * kA;
constexpr size_t OFF_BV1    = OFF_WV1  + (size_t)kS * kH;
constexpr size_t OFF_WV2    = OFF_BV1  + kH;
constexpr size_t OFF_BV2    = OFF_WV2  + (size_t)kH * kH;
constexpr size_t OFF_WV3    = OFF_BV2  + kH;
constexpr size_t OFF_BV3    = OFF_WV3  + (size_t)kH * kH;
constexpr size_t OFF_WV4    = OFF_BV3  + kH;
constexpr size_t OFF_BV4    = OFF_WV4  + (size_t)kH * kN;
constexpr size_t OFF_WL1    = OFF_BV4  + kN;
constexpr size_t OFF_BL1    = OFF_WL1  + (size_t)kS * kH;
constexpr size_t OFF_WEXP   = OFF_BL1  + kH;
constexpr size_t OFF_BEXP   = OFF_WEXP + (size_t)kN * kH * kA;
constexpr size_t OFF_TA     = OFF_BEXP + (size_t)kN * kA;
constexpr size_t OFF_TB     = OFF_TA   + (size_t)kB * kH;
constexpr size_t OFF_VALUES = OFF_TB   + (size_t)kB * kH;
constexpr size_t OFF_DIST   = OFF_VALUES + (size_t)kB * kN;
} // namespace

// --- dtype detection: low 16 bits of fp32 N(0,1) words are uniform mantissa;
// for packed bf16 they are a bf16 whose exponent field sits in [118,135].
__global__ void detect_kernel(const unsigned int* __restrict__ s_raw, int* __restrict__ flag) {
    if (threadIdx.x == 0) {
        int c = 0;
        for (int i = 0; i < 256; ++i) {
            unsigned e = (s_raw[i] >> 7) & 0xFFu;
            if (e >= 118u && e <= 135u) c++;
        }
        *flag = (c > 128) ? 1 : 0;
    }
}

__global__ void convert_kernel(const void* __restrict__ src, float* __restrict__ dst,
                               int n, const int* __restrict__ flag) {
    const int bf = *flag;
    int i = blockIdx.x * blockDim.x + threadIdx.x;
    const int stride = gridDim.x * blockDim.x;
    if (bf) {
        const unsigned short* p = (const unsigned short*)src;
        for (; i < n; i += stride)
            dst[i] = __uint_as_float(((unsigned int)p[i]) << 16);
    } else {
        const float* p = (const float*)src;
        for (; i < n; i += stride) dst[i] = p[i];
    }
}

// --- generic fp32 GEMM: C[M,N] = act(A[M,K] @ W[K,N] + bias), 64x64 tile, 4x4/thread
__launch_bounds__(256)
__global__ void gemm_bias_act(const float* __restrict__ A, const float* __restrict__ W,
                              const float* __restrict__ bias, float* __restrict__ C,
                              int M, int K, int N, int do_relu) {
    (void)M;
    constexpr int BK = 16;
    __shared__ float As[BK][68];   // transposed [k][m], padded: float4-aligned rows, 2-way banks
    __shared__ float Bs[BK][64];   // [k][n]
    const int tid = threadIdx.x;
    const int tx = tid & 15, ty = tid >> 4;
    const int m0 = blockIdx.y * 64, n0 = blockIdx.x * 64;
    float acc[4][4] = {};
    const int ar = tid >> 2, av = tid & 3;   // A tile: 64 rows x 4 float4
    const int br = tid >> 4, bv = tid & 15;  // B tile: 16 rows x 16 float4
    const float* Aptr = A + (size_t)(m0 + ar) * K + av * 4;
    const float* Bptr = W + (size_t)br * N + n0 + bv * 4;

    for (int k0 = 0; k0 < K; k0 += BK) {
        float4 a4 = *(const float4*)(Aptr + k0);
        float4 b4 = *(const float4*)(Bptr + (size_t)k0 * N);
        As[av * 4 + 0][ar] = a4.x;
        As[av * 4 + 1][ar] = a4.y;
        As[av * 4 + 2][ar] = a4.z;
        As[av * 4 + 3][ar] = a4.w;
        *(float4*)&Bs[br][bv * 4] = b4;
        __syncthreads();
#pragma unroll
        for (int k = 0; k < BK; ++k) {
            const float4 af = *(const float4*)&As[k][ty * 4];
            const float4 bf = *(const float4*)&Bs[k][tx * 4];
            const float ai[4] = {af.x, af.y, af.z, af.w};
            const float bj[4] = {bf.x, bf.y, bf.z, bf.w};
#pragma unroll
            for (int i = 0; i < 4; ++i)
#pragma unroll
                for (int j = 0; j < 4; ++j)
                    acc[i][j] = fmaf(ai[i], bj[j], acc[i][j]);
        }
        __syncthreads();
    }
#pragma unroll
    for (int i = 0; i < 4; ++i) {
        const int row = m0 + ty * 4 + i;
        float o[4];
#pragma unroll
        for (int j = 0; j < 4; ++j) {
            float v = acc[i][j] + bias[n0 + tx * 4 + j];
            if (do_relu) v = fmaxf(v, 0.f);
            o[j] = v;
        }
        *(float4*)&C[(size_t)row * N + n0 + tx * 4] = *(const float4*)o;
    }
}

// --- expert heads fused with tanh + distance: per block: 64 rows x 2 experts,
// dist[b, n] = sqrt(sum_a (tanh(h[b]@Wexp[n,:,a]+bexp[n,a]) - a_in[b,a])^2 + 0.01)
__launch_bounds__(256)
__global__ void expert_dist_kernel(const float* __restrict__ h, const float* __restrict__ Wexp,
                                   const float* __restrict__ bexp, const float* __restrict__ a_in,
                                   float* __restrict__ dist) {
    __shared__ float As[32][68];   // transposed h tile [k][m]
    __shared__ float Bs[32][64];   // [k][expert*32 + a]
    __shared__ float as_[64][32];  // action tile
    __shared__ float sq[64][17];   // per-(row, tx) partial squared dists
    const int tid = threadIdx.x;
    const int tx = tid & 15, ty = tid >> 4;
    const int m0 = blockIdx.x * 64;   // x = row tiles so consecutive blocks share the W slab
    const int n0 = blockIdx.y * 2;
    float acc[4][4] = {};

#pragma unroll
    for (int t = 0; t < 2; ++t) {
        const int idx = tid + t * 256;
        const int r = idx >> 3, c = (idx & 7) * 4;
        *(float4*)&as_[r][c] = *(const float4*)(a_in + (size_t)(m0 + r) * kA + c);
    }

    const size_t wstride = (size_t)kH * kA;
    for (int k0 = 0; k0 < kH; k0 += 32) {
#pragma unroll
        for (int t = 0; t < 2; ++t) {
            const int idx = tid + t * 256;
            const int r = idx >> 3, c = (idx & 7) * 4;  // h tile: 64 rows x 8 float4
            float4 a4 = *(const float4*)(h + (size_t)(m0 + r) * kH + k0 + c);
            As[c + 0][r] = a4.x;
            As[c + 1][r] = a4.y;
            As[c + 2][r] = a4.z;
            As[c + 3][r] = a4.w;
            const int kk = idx >> 4, c4 = idx & 15;     // W tile: 32 k x 16 float4
            const int e = c4 >> 3, la = (c4 & 7) * 4;
            float4 b4 = *(const float4*)(Wexp + (size_t)(n0 + e) * wstride + (size_t)(k0 + kk) * kA + la);
            *(float4*)&Bs[kk][c4 * 4] = b4;
        }
        __syncthreads();
#pragma unroll
        for (int k = 0; k < 32; ++k) {
            const float4 af = *(const float4*)&As[k][ty * 4];
            const float4 bf = *(const float4*)&Bs[k][tx * 4];
            const float ai[4] = {af.x, af.y, af.z, af.w};
            const float bj[4] = {bf.x, bf.y, bf.z, bf.w};
#pragma unroll
            for (int i = 0; i < 4; ++i)
#pragma unroll
                for (int j = 0; j < 4; ++j)
                    acc[i][j] = fmaf(ai[i], bj[j], acc[i][j]);
        }
        __syncthreads();
    }

    const int e = tx >> 3;
    const int la = (tx & 7) * 4;
    float bex[4];
#pragma unroll
    for (int j = 0; j < 4; ++j) bex[j] = bexp[(size_t)(n0 + e) * kA + la + j];
#pragma unroll
    for (int i = 0; i < 4; ++i) {
        const int row = ty * 4 + i;
        float p = 0.f;
#pragma unroll
        for (int j = 0; j < 4; ++j) {
            const float c = tanhf(acc[i][j] + bex[j]);  // MAX_A = 1.0
            const float d = c - as_[row][la + j];
            p = fmaf(d, d, p);
        }
        sq[row][tx] = p;
    }
    __syncthreads();
    if (tid < 128) {
        const int row = tid >> 1, e2 = tid & 1;
        float s = 0.f;
#pragma unroll
        for (int j = 0; j < 8; ++j) s += sq[row][e2 * 8 + j];
        dist[(size_t)(m0 + row) * kN + n0 + e2] = sqrtf(s + 0.01f);
    }
}

// --- softmax(-dist) . values per row
__launch_bounds__(256)
__global__ void final_kernel(const float* __restrict__ dist, const float* __restrict__ values,
                             const int* __restrict__ flag, void* __restrict__ out) {
    const int b = blockIdx.x;
    const int n = threadIdx.x;
    const float d = dist[(size_t)b * kN + n];
    const float v = values[(size_t)b * kN + n];
    const int wid = n >> 6, lane = n & 63;
    __shared__ float red[8];
    __shared__ float rw[4], rwv[4];

    float m = d;
    for (int off = 32; off > 0; off >>= 1) m = fminf(m, __shfl_down(m, off));
    if (lane == 0) red[wid] = m;
    __syncthreads();
    if (n == 0) red[4] = fminf(fminf(red[0], red[1]), fminf(red[2], red[3]));
    __syncthreads();
    const float dmin = red[4];

    float w = expf(dmin - d);  // softmax(-d) with max-subtract
    float wv = w * v;
    for (int off = 32; off > 0; off >>= 1) {
        w += __shfl_down(w, off);
        wv += __shfl_down(wv, off);
    }
    if (lane == 0) { rw[wid] = w; rwv[wid] = wv; }
    __syncthreads();
    if (n == 0) {
        const float sw = rw[0] + rw[1] + rw[2] + rw[3];
        const float swv = rwv[0] + rwv[1] + rwv[2] + rwv[3];
        const float o = swv / sw;
        if (*flag) ((__hip_bfloat16*)out)[b] = __float2bfloat16(o);
        else       ((float*)out)[b] = o;
    }
}

extern "C" void kernel_launch(void* const* d_in, const int* in_sizes, int n_in,
                              void* d_out, int out_size, void* d_ws, size_t ws_size,
                              hipStream_t stream) {
    (void)in_sizes; (void)n_in; (void)out_size; (void)ws_size;
    float* ws = (float*)d_ws;
    int* flag = (int*)ws;

    detect_kernel<<<1, 64, 0, stream>>>((const unsigned int*)d_in[0], flag);

    const size_t offs[14] = {OFF_S, OFF_A, OFF_WV1, OFF_BV1, OFF_WV2, OFF_BV2, OFF_WV3,
                             OFF_BV3, OFF_WV4, OFF_BV4, OFF_WL1, OFF_BL1, OFF_WEXP, OFF_BEXP};
    const int ns[14] = {kB * kS, kB * kA, kS * kH, kH, kH * kH, kH, kH * kH,
                        kH, kH * kN, kN, kS * kH, kH, kN * kH * kA, kN * kA};
    for (int i = 0; i < 14; ++i) {
        int blocks = (ns[i] + 1023) / 1024;
        if (blocks > 8192) blocks = 8192;
        if (blocks < 1) blocks = 1;
        convert_kernel<<<blocks, 256, 0, stream>>>(d_in[i], ws + offs[i], ns[i], flag);
    }

    float* c_s    = ws + OFF_S;
    float* c_a    = ws + OFF_A;
    float* tA     = ws + OFF_TA;
    float* tB     = ws + OFF_TB;
    float* values = ws + OFF_VALUES;
    float* dist   = ws + OFF_DIST;

    // value MLP
    gemm_bias_act<<<dim3(kH / 64, kB / 64), 256, 0, stream>>>(c_s, ws + OFF_WV1, ws + OFF_BV1, tA, kB, kS, kH, 1);
    gemm_bias_act<<<dim3(kH / 64, kB / 64), 256, 0, stream>>>(tA, ws + OFF_WV2, ws + OFF_BV2, tB, kB, kH, kH, 1);
    gemm_bias_act<<<dim3(kH / 64, kB / 64), 256, 0, stream>>>(tB, ws + OFF_WV3, ws + OFF_BV3, tA, kB, kH, kH, 1);
    gemm_bias_act<<<dim3(kN / 64, kB / 64), 256, 0, stream>>>(tA, ws + OFF_WV4, ws + OFF_BV4, values, kB, kH, kN, 0);
    // location hidden (tB is free after GEMM3 consumed it)
    gemm_bias_act<<<dim3(kH / 64, kB / 64), 256, 0, stream>>>(c_s, ws + OFF_WL1, ws + OFF_BL1, tB, kB, kS, kH, 1);
    // fused expert heads -> tanh -> distance
    expert_dist_kernel<<<dim3(kB / 64, kN / 2), 256, 0, stream>>>(tB, ws + OFF_WEXP, ws + OFF_BEXP, c_a, dist);
    // softmax-weighted value readout
    final_kernel<<<kB, 256, 0, stream>>>(dist, values, flag, d_out);
}

// Round 2
// 368.857 us; speedup vs baseline: 3.7439x; 3.7439x over previous
//
#include <hip/hip_runtime.h>
#include <hip/hip_bf16.h>

// Net_40089224741482 round 2: f16 MFMA (fp32 accum) for all GEMMs.
//  - inputs detected fp32 vs bf16-packed at runtime; bf16->f16 is exact
//  - weights pre-transposed to [N][K] f16 so A and B fragments are contiguous
//  - expert GEMM fused with tanh + ||c-a|| distance (centroids never hit HBM)

typedef _Float16 half8 __attribute__((ext_vector_type(8)));
typedef float floatx16 __attribute__((ext_vector_type(16)));

namespace {
constexpr int kB = 4096, kS = 128, kA = 32, kH = 1024, kN = 256;
constexpr size_t al(size_t x) { return (x + 255) & ~size_t(255); }
constexpr size_t OFF_FLAG  = 0;
constexpr size_t OFF_S16   = 256;
constexpr size_t OFF_WV1T  = OFF_S16   + al((size_t)kB * kS * 2);
constexpr size_t OFF_WV2T  = OFF_WV1T  + al((size_t)kS * kH * 2);
constexpr size_t OFF_WV3T  = OFF_WV2T  + al((size_t)kH * kH * 2);
constexpr size_t OFF_WV4T  = OFF_WV3T  + al((size_t)kH * kH * 2);
constexpr size_t OFF_WL1T  = OFF_WV4T  + al((size_t)kH * kN * 2);
constexpr size_t OFF_WEXPT = OFF_WL1T  + al((size_t)kS * kH * 2);
constexpr size_t OFF_BUF1  = OFF_WEXPT + al((size_t)kN * kA * kH * 2);
constexpr size_t OFF_BUF2  = OFF_BUF1  + al((size_t)kB * kH * 2);
constexpr size_t OFF_VAL   = OFF_BUF2  + al((size_t)kB * kH * 2);
constexpr size_t OFF_DIST  = OFF_VAL   + al((size_t)kB * kN * 4);
} // namespace

__device__ __forceinline__ float ldraw(const void* p, size_t i, int bf) {
    if (bf) return __uint_as_float(((unsigned)((const unsigned short*)p)[i]) << 16);
    return ((const float*)p)[i];
}

// --- dtype detection: low 16 bits of fp32 N(0,1) are uniform mantissa bits;
// for packed bf16 they are a bf16 value whose exponent field sits near 127.
__global__ void detect_kernel(const unsigned int* __restrict__ s_raw, int* __restrict__ flag) {
    if (threadIdx.x == 0) {
        int c = 0;
        for (int i = 0; i < 256; ++i) {
            unsigned e = (s_raw[i] >> 7) & 0xFFu;
            if (e >= 118u && e <= 135u) c++;
        }
        *flag = (c > 128) ? 1 : 0;
    }
}

__global__ void convert_to_f16(const void* __restrict__ src, _Float16* __restrict__ dst,
                               int n, const int* __restrict__ flag) {
    const int bf = *flag;
    int i = blockIdx.x * blockDim.x + threadIdx.x;
    const int stride = gridDim.x * blockDim.x;
    for (; i < n; i += stride) dst[i] = (_Float16)ldraw(src, i, bf);
}

// src [Z][K][N] (fp32 or bf16) -> dst [Z][N][K] f16, 32x32 LDS-tiled
__global__ void transpose_to_f16(const void* __restrict__ src, _Float16* __restrict__ dst,
                                 int K, int N, const int* __restrict__ flag) {
    __shared__ float tile[32][33];
    const int bf = *flag;
    const size_t zo = (size_t)blockIdx.z * K * N;
    const int n0 = blockIdx.x * 32, k0 = blockIdx.y * 32;
    const int tx = threadIdx.x, ty = threadIdx.y;
#pragma unroll
    for (int j = 0; j < 32; j += 8)
        tile[ty + j][tx] = ldraw(src, zo + (size_t)(k0 + ty + j) * N + n0 + tx, bf);
    __syncthreads();
#pragma unroll
    for (int j = 0; j < 32; j += 8)
        dst[zo + (size_t)(n0 + ty + j) * K + k0 + tx] = (_Float16)tile[tx][ty + j];
}

// --- f16 MFMA GEMM: C[M,N] = act(A[M,K] @ Bt[N,K]^T + bias)
// block 256 thr = 4 waves, tile 128x128, wave 64x64 = 2x2 mfma_32x32x16 accs
template <int DO_RELU, int OUT_F16>
__launch_bounds__(256)
__global__ void mfma_gemm(const _Float16* __restrict__ A, const _Float16* __restrict__ Bt,
                          const void* __restrict__ bias_raw, void* __restrict__ Cout,
                          const int* __restrict__ flagp, int N, int K) {
    __shared__ _Float16 As[2][128][16];
    __shared__ _Float16 Bs[2][128][16];
    const int tid = threadIdx.x;
    const int lane = tid & 63;
    const int w = tid >> 6, wr = w >> 1, wc = w & 1;
    const int m0 = blockIdx.y * 128, n0 = blockIdx.x * 128;

    // staging: slot = tid (+256): row = slot>>2, k-quarter q = slot&3 (8 f16 = 16B)
    const int r0 = tid >> 2, q = tid & 3;
    const _Float16* gA0 = A + (size_t)(m0 + r0) * K + q * 8;
    const _Float16* gA1 = gA0 + (size_t)64 * K;
    const _Float16* gB0 = Bt + (size_t)(n0 + r0) * K + q * 8;
    const _Float16* gB1 = gB0 + (size_t)64 * K;
    _Float16* lA0 = &As[q >> 1][r0][(q & 1) * 8];
    _Float16* lA1 = &As[q >> 1][r0 + 64][(q & 1) * 8];
    _Float16* lB0 = &Bs[q >> 1][r0][(q & 1) * 8];
    _Float16* lB1 = &Bs[q >> 1][r0 + 64][(q & 1) * 8];

    const int am = lane & 31;
    const int ah = (lane >> 5) * 8;
    const _Float16* pA0 = &As[0][wr * 64 + am][ah];
    const _Float16* pA1 = &As[0][wr * 64 + 32 + am][ah];
    const _Float16* pB0 = &Bs[0][wc * 64 + am][ah];
    const _Float16* pB1 = &Bs[0][wc * 64 + 32 + am][ah];

    floatx16 zero;
#pragma unroll
    for (int i = 0; i < 16; ++i) zero[i] = 0.f;
    floatx16 acc[2][2] = {zero, zero, zero, zero};

    for (int k0 = 0; k0 < K; k0 += 32) {
        float4 a0 = *(const float4*)(gA0 + k0);
        float4 a1 = *(const float4*)(gA1 + k0);
        float4 b0 = *(const float4*)(gB0 + k0);
        float4 b1 = *(const float4*)(gB1 + k0);
        __syncthreads();
        *(float4*)lA0 = a0;
        *(float4*)lA1 = a1;
        *(float4*)lB0 = b0;
        *(float4*)lB1 = b1;
        __syncthreads();
#pragma unroll
        for (int ks = 0; ks < 2; ++ks) {
            const int off = ks * (128 * 16);
            half8 af0 = *(const half8*)(pA0 + off);
            half8 af1 = *(const half8*)(pA1 + off);
            half8 bf0 = *(const half8*)(pB0 + off);
            half8 bf1 = *(const half8*)(pB1 + off);
            acc[0][0] = __builtin_amdgcn_mfma_f32_32x32x16_f16(af0, bf0, acc[0][0], 0, 0, 0);
            acc[0][1] = __builtin_amdgcn_mfma_f32_32x32x16_f16(af0, bf1, acc[0][1], 0, 0, 0);
            acc[1][0] = __builtin_amdgcn_mfma_f32_32x32x16_f16(af1, bf0, acc[1][0], 0, 0, 0);
            acc[1][1] = __builtin_amdgcn_mfma_f32_32x32x16_f16(af1, bf1, acc[1][1], 0, 0, 0);
        }
    }

    const int bf = *flagp;
    const int half = lane >> 5;
#pragma unroll
    for (int mi = 0; mi < 2; ++mi)
#pragma unroll
        for (int ni = 0; ni < 2; ++ni) {
            const int Rb = m0 + wr * 64 + mi * 32;
            const int Cb = n0 + wc * 64 + ni * 32 + am;
            const float bv = ldraw(bias_raw, Cb, bf);
#pragma unroll
            for (int rr = 0; rr < 16; ++rr) {
                const int row = Rb + (rr & 3) + 8 * (rr >> 2) + 4 * half;
                float x = acc[mi][ni][rr] + bv;
                if (DO_RELU) x = fmaxf(x, 0.f);
                if (OUT_F16) ((_Float16*)Cout)[(size_t)row * N + Cb] = (_Float16)x;
                else ((float*)Cout)[(size_t)row * N + Cb] = x;
            }
        }
}

// --- expert GEMM [B,K]x[N*A,K]^T fused with tanh + distance reduction over a
__launch_bounds__(256)
__global__ void expert_dist_mfma(const _Float16* __restrict__ A, const _Float16* __restrict__ Bt,
                                 const void* __restrict__ bexp_raw, const void* __restrict__ a_raw,
                                 float* __restrict__ dist, const int* __restrict__ flagp) {
    constexpr int K = kH;
    __shared__ _Float16 As[2][128][16];
    __shared__ _Float16 Bs[2][128][16];
    const int tid = threadIdx.x;
    const int lane = tid & 63;
    const int w = tid >> 6, wr = w >> 1, wc = w & 1;
    const int m0 = blockIdx.y * 128, n0 = blockIdx.x * 128;

    const int r0 = tid >> 2, q = tid & 3;
    const _Float16* gA0 = A + (size_t)(m0 + r0) * K + q * 8;
    const _Float16* gA1 = gA0 + (size_t)64 * K;
    const _Float16* gB0 = Bt + (size_t)(n0 + r0) * K + q * 8;
    const _Float16* gB1 = gB0 + (size_t)64 * K;
    _Float16* lA0 = &As[q >> 1][r0][(q & 1) * 8];
    _Float16* lA1 = &As[q >> 1][r0 + 64][(q & 1) * 8];
    _Float16* lB0 = &Bs[q >> 1][r0][(q & 1) * 8];
    _Float16* lB1 = &Bs[q >> 1][r0 + 64][(q & 1) * 8];

    const int am = lane & 31;
    const int ah = (lane >> 5) * 8;
    const _Float16* pA0 = &As[0][wr * 64 + am][ah];
    const _Float16* pA1 = &As[0][wr * 64 + 32 + am][ah];
    const _Float16* pB0 = &Bs[0][wc * 64 + am][ah];
    const _Float16* pB1 = &Bs[0][wc * 64 + 32 + am][ah];

    floatx16 zero;
#pragma unroll
    for (int i = 0; i < 16; ++i) zero[i] = 0.f;
    floatx16 acc[2][2] = {zero, zero, zero, zero};

    for (int k0 = 0; k0 < K; k0 += 32) {
        float4 a0 = *(const float4*)(gA0 + k0);
        float4 a1 = *(const float4*)(gA1 + k0);
        float4 b0 = *(const float4*)(gB0 + k0);
        float4 b1 = *(const float4*)(gB1 + k0);
        __syncthreads();
        *(float4*)lA0 = a0;
        *(float4*)lA1 = a1;
        *(float4*)lB0 = b0;
        *(float4*)lB1 = b1;
        __syncthreads();
#pragma unroll
        for (int ks = 0; ks < 2; ++ks) {
            const int off = ks * (128 * 16);
            half8 af0 = *(const half8*)(pA0 + off);
            half8 af1 = *(const half8*)(pA1 + off);
            half8 bf0 = *(const half8*)(pB0 + off);
            half8 bf1 = *(const half8*)(pB1 + off);
            acc[0][0] = __builtin_amdgcn_mfma_f32_32x32x16_f16(af0, bf0, acc[0][0], 0, 0, 0);
            acc[0][1] = __builtin_amdgcn_mfma_f32_32x32x16_f16(af0, bf1, acc[0][1], 0, 0, 0);
            acc[1][0] = __builtin_amdgcn_mfma_f32_32x32x16_f16(af1, bf0, acc[1][0], 0, 0, 0);
            acc[1][1] = __builtin_amdgcn_mfma_f32_32x32x16_f16(af1, bf1, acc[1][1], 0, 0, 0);
        }
    }

    __syncthreads();  // done with As as fragments; reuse as reduction scratch
    float* red = (float*)&As[0][0][0];  // [wave][half][16]
    const int bf = *flagp;
    const int half = lane >> 5;

#pragma unroll
    for (int mi = 0; mi < 2; ++mi) {
        const int Rb = m0 + wr * 64 + mi * 32;
        float av[16];
#pragma unroll
        for (int rr = 0; rr < 16; ++rr) {
            const int row = Rb + (rr & 3) + 8 * (rr >> 2) + 4 * half;
            av[rr] = ldraw(a_raw, (size_t)row * kA + am, bf);
        }
#pragma unroll
        for (int ni = 0; ni < 2; ++ni) {
            const int Cb = n0 + wc * 64 + ni * 32;  // 32-aligned -> one expert
            const int e = Cb >> 5;
            const float be = ldraw(bexp_raw, Cb + am, bf);
            float s[16];
#pragma unroll
            for (int rr = 0; rr < 16; ++rr) {
                const float c = tanhf(acc[mi][ni][rr] + be);  // MAX_A = 1.0
                const float d = c - av[rr];
                s[rr] = d * d;
            }
#pragma unroll
            for (int msk = 1; msk <= 16; msk <<= 1)
#pragma unroll
                for (int rr = 0; rr < 16; ++rr)
                    s[rr] += __shfl_xor(s[rr], msk, 64);
            if (am == 0) {
#pragma unroll
                for (int rr = 0; rr < 16; ++rr) red[w * 32 + half * 16 + rr] = s[rr];
            }
            // same-wave LDS RAW; compiler inserts lgkmcnt wait
            if (am < 16) {
                const float ss = red[w * 32 + half * 16 + am];
                const int row = Rb + (am & 3) + 8 * (am >> 2) + 4 * half;
                dist[(size_t)row * kN + e] = sqrtf(ss + 0.01f);
            }
        }
    }
}

// --- softmax(-dist) . values per row
__launch_bounds__(256)
__global__ void final_kernel(const float* __restrict__ dist, const float* __restrict__ values,
                             const int* __restrict__ flag, void* __restrict__ out) {
    const int b = blockIdx.x;
    const int n = threadIdx.x;
    const float d = dist[(size_t)b * kN + n];
    const float v = values[(size_t)b * kN + n];
    const int wid = n >> 6, lane = n & 63;
    __shared__ float red[8];
    __shared__ float rw[4], rwv[4];

    float m = d;
    for (int off = 32; off > 0; off >>= 1) m = fminf(m, __shfl_down(m, off));
    if (lane == 0) red[wid] = m;
    __syncthreads();
    if (n == 0) red[4] = fminf(fminf(red[0], red[1]), fminf(red[2], red[3]));
    __syncthreads();
    const float dmin = red[4];

    float wgt = expf(dmin - d);
    float wv = wgt * v;
    for (int off = 32; off > 0; off >>= 1) {
        wgt += __shfl_down(wgt, off);
        wv += __shfl_down(wv, off);
    }
    if (lane == 0) { rw[wid] = wgt; rwv[wid] = wv; }
    __syncthreads();
    if (n == 0) {
        const float sw = rw[0] + rw[1] + rw[2] + rw[3];
        const float swv = rwv[0] + rwv[1] + rwv[2] + rwv[3];
        const float o = swv / sw;
        if (*flag) ((__hip_bfloat16*)out)[b] = __float2bfloat16(o);
        else       ((float*)out)[b] = o;
    }
}

extern "C" void kernel_launch(void* const* d_in, const int* in_sizes, int n_in,
                              void* d_out, int out_size, void* d_ws, size_t ws_size,
                              hipStream_t stream) {
    (void)in_sizes; (void)n_in; (void)out_size; (void)ws_size;
    char* ws = (char*)d_ws;
    int* flag = (int*)(ws + OFF_FLAG);
    _Float16* s16   = (_Float16*)(ws + OFF_S16);
    _Float16* wv1t  = (_Float16*)(ws + OFF_WV1T);
    _Float16* wv2t  = (_Float16*)(ws + OFF_WV2T);
    _Float16* wv3t  = (_Float16*)(ws + OFF_WV3T);
    _Float16* wv4t  = (_Float16*)(ws + OFF_WV4T);
    _Float16* wl1t  = (_Float16*)(ws + OFF_WL1T);
    _Float16* wexpt = (_Float16*)(ws + OFF_WEXPT);
    _Float16* buf1  = (_Float16*)(ws + OFF_BUF1);
    _Float16* buf2  = (_Float16*)(ws + OFF_BUF2);
    float* values   = (float*)(ws + OFF_VAL);
    float* dist     = (float*)(ws + OFF_DIST);

    detect_kernel<<<1, 64, 0, stream>>>((const unsigned int*)d_in[0], flag);
    convert_to_f16<<<512, 256, 0, stream>>>(d_in[0], s16, kB * kS, flag);

    dim3 tb(32, 8);
    transpose_to_f16<<<dim3(kH / 32, kS / 32, 1), tb, 0, stream>>>(d_in[2],  wv1t,  kS, kH, flag);
    transpose_to_f16<<<dim3(kH / 32, kH / 32, 1), tb, 0, stream>>>(d_in[4],  wv2t,  kH, kH, flag);
    transpose_to_f16<<<dim3(kH / 32, kH / 32, 1), tb, 0, stream>>>(d_in[6],  wv3t,  kH, kH, flag);
    transpose_to_f16<<<dim3(kN / 32, kH / 32, 1), tb, 0, stream>>>(d_in[8],  wv4t,  kH, kN, flag);
    transpose_to_f16<<<dim3(kH / 32, kS / 32, 1), tb, 0, stream>>>(d_in[10], wl1t,  kS, kH, flag);
    transpose_to_f16<<<dim3(kA / 32, kH / 32, kN), tb, 0, stream>>>(d_in[12], wexpt, kH, kA, flag);

    mfma_gemm<1, 1><<<dim3(kH / 128, kB / 128), 256, 0, stream>>>(s16,  wv1t, d_in[3], buf1, flag, kH, kS);
    mfma_gemm<1, 1><<<dim3(kH / 128, kB / 128), 256, 0, stream>>>(buf1, wv2t, d_in[5], buf2, flag, kH, kH);
    mfma_gemm<1, 1><<<dim3(kH / 128, kB / 128), 256, 0, stream>>>(buf2, wv3t, d_in[7], buf1, flag, kH, kH);
    mfma_gemm<0, 0><<<dim3(kN / 128, kB / 128), 256, 0, stream>>>(buf1, wv4t, d_in[9], values, flag, kN, kH);
    mfma_gemm<1, 1><<<dim3(kH / 128, kB / 128), 256, 0, stream>>>(s16,  wl1t, d_in[11], buf2, flag, kH, kS);

    expert_dist_mfma<<<dim3((kN * kA) / 128, kB / 128), 256, 0, stream>>>(
        buf2, wexpt, d_in[13], d_in[1], dist, flag);

    final_kernel<<<kB, 256, 0, stream>>>(dist, values, flag, d_out);
}